// Round 4
// baseline (95.911 us; speedup 1.0000x reference)
//
#include <hip/hip_runtime.h>
#include <hip/hip_bf16.h>

// memristor_dense: y[b,j] = sum_i A[i,2j]*2^(e[i,2j]*l[b,i]) - A[i,2j+1]*2^(e[i,2j+1]*l[b,i])
//   A[i,j] = 0.5*|w[i,j]| + max_w/18      (folds G, V_REF, 1/(K_V*k_G), G_MIN)
//   e[i,j] = log2(n_param[i,j]) + 1
//   l[b,i] = log2(2*clip(x[b,i],0,1))     (log2(0)=-inf -> exp2(-inf)=0 handles x==0 mask)
// shapes: x(128,1024), w_pos/w_neg(1024,512), b_pos/b_neg(512), n_param(1025,1024)
//
// R3 -> R4: precompute packed param table T[i][j]={A0,E0,A1,E1} (8.4MB in ws) and
// log table L[b][i] (512KB in ws) in setup2, removing the 8x-redundant per-b-tile
// log2(n_param) and 32x-redundant log2(x) from the main kernel. Main kernel staging
// is now pure float4 copies; its VALU/trans issue is only the irreducible inner
// loop (mul+exp+fma per term = 12 cyc issue -> ~10.2us chip floor).

#define LOG2F(v)  __builtin_amdgcn_logf(v)    // v_log_f32: log2(x)
#define EXP2F(v)  __builtin_amdgcn_exp2f(v)   // v_exp_f32: 2^x

#define NJ 16        // jpairs per block
#define NB 16        // batch rows per block
#define KI 64        // k-chunk
#define KROW4 65     // sP row stride in float4 (bank offset 4 -> benign)
#define LROW 68      // sL row stride in floats (17 float4s, 16B-aligned rows)

#define NPART 32     // max-partial blocks
// ws layout (bytes): [0,128)=max partials, [256, 256+8396800)=T table, then L table
#define T_OFF_B   256
#define L_OFF_B   (T_OFF_B + 525824 * 16)   // 1025*512=524800 rounded up to 525824 float4
#define NROW_T    1025

__global__ __launch_bounds__(256) void setup1_kernel(
    const float* __restrict__ w_pos, const float* __restrict__ w_neg,
    const float* __restrict__ b_pos, const float* __restrict__ b_neg,
    float* __restrict__ ws) {
  const int t = threadIdx.x, blk = blockIdx.x;
  const float4* wp4 = (const float4*)w_pos;
  const float4* wn4 = (const float4*)w_neg;
  float m = 0.0f;
  #pragma unroll 4
  for (int r = 0; r < 16; ++r) {
    int i = blk * 4096 + r * 256 + t;
    float4 a = wp4[i], b = wn4[i];
    m = fmaxf(m, fmaxf(fmaxf(fabsf(a.x), fabsf(a.y)), fmaxf(fabsf(a.z), fabsf(a.w))));
    m = fmaxf(m, fmaxf(fmaxf(fabsf(b.x), fabsf(b.y)), fmaxf(fabsf(b.z), fabsf(b.w))));
  }
  if (blk == 0) {
    m = fmaxf(m, fmaxf(fabsf(b_pos[t]), fabsf(b_pos[t + 256])));
    m = fmaxf(m, fmaxf(fabsf(b_neg[t]), fabsf(b_neg[t + 256])));
  }
  #pragma unroll
  for (int off = 32; off > 0; off >>= 1)
    m = fmaxf(m, __shfl_down(m, off, 64));
  __shared__ float sm[4];
  int lane = t & 63, wv = t >> 6;
  if (lane == 0) sm[wv] = m;
  __syncthreads();
  if (t == 0)
    ws[blk] = fmaxf(fmaxf(sm[0], sm[1]), fmaxf(sm[2], sm[3]));
}

// grid: 1153 blocks. blocks [0,1025): table row i (+ first 256 also zero y).
// blocks [1025,1153): L row b = blk-1025.
__global__ __launch_bounds__(256) void setup2_kernel(
    const float* __restrict__ x, const float* __restrict__ w_pos,
    const float* __restrict__ w_neg, const float* __restrict__ b_pos,
    const float* __restrict__ b_neg, const float* __restrict__ n_param,
    float* __restrict__ y, float* __restrict__ ws) {
  const int t = threadIdx.x, blk = blockIdx.x;
  float mw = 0.0f;
  #pragma unroll
  for (int i = 0; i < NPART; ++i) mw = fmaxf(mw, ws[i]);
  const float c0 = mw * (0.05f / 0.9f);   // G_MIN*V_REF/(K_V*k_G) = max_w/18

  if (blk < NROW_T) {
    const int i = blk;
    const float2* np2 = (const float2*)n_param;
    float4* T4 = (float4*)((char*)ws + T_OFF_B);
    #pragma unroll
    for (int h = 0; h < 2; ++h) {
      int j = t + h * 256;
      float wp, wn;
      if (i < 1024) { wp = w_pos[i * 512 + j]; wn = w_neg[i * 512 + j]; }
      else          { wp = b_pos[j];           wn = b_neg[j]; }
      float2 np = np2[i * 512 + j];
      T4[i * 512 + j] = make_float4(
          fmaf(0.5f, fabsf(wp), c0), LOG2F(np.x) + 1.0f,
          fmaf(0.5f, fabsf(wn), c0), LOG2F(np.y) + 1.0f);
    }
    if (blk < 256) y[blk * 256 + t] = 0.0f;   // zero the atomicAdd target
  } else {
    const int b = blk - NROW_T;
    float* L = (float*)((char*)ws + L_OFF_B);
    #pragma unroll
    for (int h = 0; h < 4; ++h) {
      int i = t + h * 256;
      float v = x[b * 1024 + i];
      v = fminf(fmaxf(v, 0.0f), 1.0f);
      L[b * 1024 + i] = LOG2F(2.0f * v);
    }
  }
}

__global__ __launch_bounds__(256) void memristor_kernel(
    const float* __restrict__ ws_c, float* __restrict__ y) {
  __shared__ float4 sP[NJ * KROW4];
  __shared__ float  sL[NB * LROW];

  const float4* T4 = (const float4*)((const char*)ws_c + T_OFF_B);
  const float*  L  = (const float*)((const char*)ws_c + L_OFF_B);

  const int j0 = blockIdx.x * NJ;   // 32 j-tiles
  const int b0 = blockIdx.y * NB;   // 8 b-tiles
  const int zt = blockIdx.z;        // 4-way i-split: rows [zt*256, zt*256+256)
  const int t  = threadIdx.x;
  const int jj = t & 15;
  const int bb = t >> 4;
  float accP = 0.0f, accN = 0.0f;

  for (int c = 0; c < 4; ++c) {
    const int i0 = zt * 256 + c * KI;
    // stage L slice: 16 rows x 64 -> one float4 per thread
    {
      int bl = t >> 4, k4 = t & 15;
      float4 v = *(const float4*)&L[(b0 + bl) * 1024 + i0 + k4 * 4];
      *(float4*)&sL[bl * LROW + k4 * 4] = v;
    }
    // stage param slice: 16 jpairs x 64 k -> 4 float4 per thread (pure copy)
    #pragma unroll
    for (int r = 0; r < (NJ * KI) / 256; ++r) {
      int idx = r * 256 + t;
      int jl = idx & (NJ - 1);
      int il = idx >> 4;
      sP[jl * KROW4 + il] = T4[(i0 + il) * 512 + j0 + jl];
    }
    __syncthreads();
    const float4* pP = &sP[jj * KROW4];
    const float*  pL = &sL[bb * LROW];
    #pragma unroll 8
    for (int k = 0; k < KI; ++k) {
      float4 p = pP[k];
      float l  = pL[k];
      accP = fmaf(p.x, EXP2F(p.y * l), accP);
      accN = fmaf(p.z, EXP2F(p.w * l), accN);
    }
    __syncthreads();
  }

  if (zt == 3) {
    // bias row i = 1024: inp = 1 -> vr = 2 -> 2^e
    float4 p = T4[1024 * 512 + j0 + jj];
    accP = fmaf(p.x, EXP2F(p.y), accP);
    accN = fmaf(p.z, EXP2F(p.w), accN);
  }

  atomicAdd(&y[(b0 + bb) * 512 + (j0 + jj)], accP - accN);
}

extern "C" void kernel_launch(void* const* d_in, const int* in_sizes, int n_in,
                              void* d_out, int out_size, void* d_ws, size_t ws_size,
                              hipStream_t stream) {
  const float* x       = (const float*)d_in[0];
  const float* w_pos   = (const float*)d_in[1];
  const float* w_neg   = (const float*)d_in[2];
  const float* b_pos   = (const float*)d_in[3];
  const float* b_neg   = (const float*)d_in[4];
  const float* n_param = (const float*)d_in[5];
  float* y   = (float*)d_out;
  float* wsf = (float*)d_ws;

  setup1_kernel<<<dim3(NPART), dim3(256), 0, stream>>>(
      w_pos, w_neg, b_pos, b_neg, wsf);

  setup2_kernel<<<dim3(NROW_T + 128), dim3(256), 0, stream>>>(
      x, w_pos, w_neg, b_pos, b_neg, n_param, y, wsf);

  memristor_kernel<<<dim3(32, 8, 4), dim3(256), 0, stream>>>(wsf, y);
}

// Round 5
// 95.630 us; speedup vs baseline: 1.0029x; 1.0029x over previous
//
#include <hip/hip_runtime.h>
#include <hip/hip_bf16.h>

// memristor_dense: y[b,j] = sum_i A[i,2j]*2^(e[i,2j]*l[b,i]) - A[i,2j+1]*2^(e[i,2j+1]*l[b,i])
//   A[i,j] = 0.5*|w[i,j]| + max_w/18      (folds G, V_REF, 1/(K_V*k_G), G_MIN)
//   e[i,j] = log2(n_param[i,j]) + 1
//   l[b,i] = log2(2*clip(x[b,i],0,1))     (log2(0)=-inf -> exp2(-inf)=0 handles x==0 mask)
// shapes: x(128,1024), w_pos/w_neg(1024,512), b_pos/b_neg(512), n_param(1025,1024)
//
// R4 -> R5: revert R4's precompute tables (regressed: extra dispatch + 17MB table
// traffic > 6% trans savings). Back to R3 structure with two fixes:
//  (a) setup1 max-reduction spread over 256 blocks (was 32 -> cold 8.4MB HBM read
//      on 1/8 of the chip); main kernel reduces 256 partials (uniform loads).
//  (b) main kernel NB=32 with 512 threads: 4 b-tiles instead of 8 -> param
//      staging traffic halves (67MB -> 33.6MB L2/L3). Inner loop unchanged:
//      trans-bound (2 exp2 per k-iter = 16 cyc/SIMD, ~6.8us chip floor).

#define LOG2F(v)  __builtin_amdgcn_logf(v)    // v_log_f32: log2(x)
#define EXP2F(v)  __builtin_amdgcn_exp2f(v)   // v_exp_f32: 2^x

#define NJ 16        // jpairs per block
#define NB 32        // batch rows per block
#define KI 64        // k-chunk
#define KROW4 65     // sP row stride in float4 (bank offset 4 -> 2-way = free)
#define LROW 68      // sL row stride in floats

#define NPART 256    // max-partial blocks

__global__ __launch_bounds__(256) void setup1_kernel(
    const float* __restrict__ w_pos, const float* __restrict__ w_neg,
    const float* __restrict__ b_pos, const float* __restrict__ b_neg,
    float* __restrict__ ws) {
  const int t = threadIdx.x, blk = blockIdx.x;
  const float4* wp4 = (const float4*)w_pos;
  const float4* wn4 = (const float4*)w_neg;
  float m = 0.0f;
  // each array: 131072 float4 -> 512 per block -> 2 per thread
  #pragma unroll
  for (int r = 0; r < 2; ++r) {
    int i = blk * 512 + r * 256 + t;
    float4 a = wp4[i], b = wn4[i];
    m = fmaxf(m, fmaxf(fmaxf(fabsf(a.x), fabsf(a.y)), fmaxf(fabsf(a.z), fabsf(a.w))));
    m = fmaxf(m, fmaxf(fmaxf(fabsf(b.x), fabsf(b.y)), fmaxf(fabsf(b.z), fabsf(b.w))));
  }
  if (blk == 0) {
    m = fmaxf(m, fmaxf(fabsf(b_pos[t]), fabsf(b_pos[t + 256])));
    m = fmaxf(m, fmaxf(fabsf(b_neg[t]), fabsf(b_neg[t + 256])));
  }
  #pragma unroll
  for (int off = 32; off > 0; off >>= 1)
    m = fmaxf(m, __shfl_down(m, off, 64));
  __shared__ float sm[4];
  int lane = t & 63, wv = t >> 6;
  if (lane == 0) sm[wv] = m;
  __syncthreads();
  if (t == 0)
    ws[blk] = fmaxf(fmaxf(sm[0], sm[1]), fmaxf(sm[2], sm[3]));  // plain store
}

__global__ __launch_bounds__(512) void memristor_kernel(
    const float* __restrict__ x, const float* __restrict__ w_pos,
    const float* __restrict__ w_neg, const float* __restrict__ b_pos,
    const float* __restrict__ b_neg, const float* __restrict__ n_param,
    const float* __restrict__ ws, float* __restrict__ y) {
  __shared__ float4 sP[NJ * KROW4];
  __shared__ float  sL[NB * LROW];

  // reduce the 256 max partials (uniform float4 loads, once per block)
  const float4* mp4 = (const float4*)ws;
  float4 m4 = mp4[0];
  #pragma unroll 16
  for (int i = 1; i < NPART / 4; ++i) {
    float4 v = mp4[i];
    m4.x = fmaxf(m4.x, v.x); m4.y = fmaxf(m4.y, v.y);
    m4.z = fmaxf(m4.z, v.z); m4.w = fmaxf(m4.w, v.w);
  }
  const float mw = fmaxf(fmaxf(m4.x, m4.y), fmaxf(m4.z, m4.w));
  const float c0 = mw * (0.05f / 0.9f);   // G_MIN*V_REF/(K_V*k_G) = max_w/18

  const int j0 = blockIdx.x * NJ;   // 32 j-tiles
  const int b0 = blockIdx.y * NB;   // 4 b-tiles
  const int zt = blockIdx.z;        // 4-way i-split: rows [zt*256, zt*256+256)
  const int t  = threadIdx.x;
  const int jj = t & 15;
  const int bb = t >> 4;            // [0,32)
  float accP = 0.0f, accN = 0.0f;

  const float2* np2 = (const float2*)n_param;

  for (int c = 0; c < 4; ++c) {
    const int i0 = zt * 256 + c * KI;
    // stage x -> l = log2(2*clip(x)) : 32 rows x 64, 4 per thread
    #pragma unroll
    for (int r = 0; r < (NB * KI) / 512; ++r) {
      int idx = r * 512 + t;
      int k  = idx & (KI - 1);
      int bl = idx >> 6;
      float v = x[(b0 + bl) * 1024 + i0 + k];
      v = fminf(fmaxf(v, 0.0f), 1.0f);
      sL[bl * LROW + k] = LOG2F(2.0f * v);
    }
    // stage params as float4 {A0, E0, A1, E1} : 16 jpairs x 64 k, 2 per thread
    #pragma unroll
    for (int r = 0; r < (NJ * KI) / 512; ++r) {
      int idx = r * 512 + t;
      int jl = idx & (NJ - 1);
      int il = idx >> 4;
      int gi = i0 + il;
      float wp = w_pos[gi * 512 + j0 + jl];
      float wn = w_neg[gi * 512 + j0 + jl];
      float2 np = np2[gi * 512 + j0 + jl];   // (n[i,2j], n[i,2j+1])
      sP[jl * KROW4 + il] = make_float4(
          fmaf(0.5f, fabsf(wp), c0), LOG2F(np.x) + 1.0f,
          fmaf(0.5f, fabsf(wn), c0), LOG2F(np.y) + 1.0f);
    }
    __syncthreads();
    const float4* pP = &sP[jj * KROW4];
    const float*  pL = &sL[bb * LROW];
    #pragma unroll 8
    for (int k = 0; k < KI; ++k) {
      float4 p = pP[k];
      float l  = pL[k];
      accP = fmaf(p.x, EXP2F(p.y * l), accP);
      accN = fmaf(p.z, EXP2F(p.w * l), accN);
    }
    __syncthreads();
  }

  if (zt == 3) {
    // bias row i = 1024: inp = 1 -> vr = 2 -> 2^e
    int jg = j0 + jj;
    float2 np = np2[1024 * 512 + jg];
    float a0 = fmaf(0.5f, fabsf(b_pos[jg]), c0);
    float a1 = fmaf(0.5f, fabsf(b_neg[jg]), c0);
    accP = fmaf(a0, EXP2F(LOG2F(np.x) + 1.0f), accP);
    accN = fmaf(a1, EXP2F(LOG2F(np.y) + 1.0f), accN);
  }

  atomicAdd(&y[(b0 + bb) * 512 + (j0 + jj)], accP - accN);
}

// zero d_out (atomicAdd target) without a hipMemsetAsync dispatch cost profile:
// fold into setup1? setup1 blocks are busy with w; a 256-block kernel writing
// 256KB is ~free inside setup1 -- do it there via first 64 blocks.
__global__ __launch_bounds__(256) void zero_y_kernel(float4* __restrict__ y4) {
  y4[blockIdx.x * 256 + threadIdx.x] = make_float4(0.f, 0.f, 0.f, 0.f);
}

extern "C" void kernel_launch(void* const* d_in, const int* in_sizes, int n_in,
                              void* d_out, int out_size, void* d_ws, size_t ws_size,
                              hipStream_t stream) {
  const float* x       = (const float*)d_in[0];
  const float* w_pos   = (const float*)d_in[1];
  const float* w_neg   = (const float*)d_in[2];
  const float* b_pos   = (const float*)d_in[3];
  const float* b_neg   = (const float*)d_in[4];
  const float* n_param = (const float*)d_in[5];
  float* y   = (float*)d_out;
  float* wsf = (float*)d_ws;

  // one memset-equivalent via kernel concurrent with setup1 (both small);
  // keep as memsetAsync: it's 256KB -> ~0.1us, cheaper than a kernel node.
  (void)hipMemsetAsync(d_out, 0, (size_t)out_size * 4, stream);

  setup1_kernel<<<dim3(NPART), dim3(256), 0, stream>>>(
      w_pos, w_neg, b_pos, b_neg, wsf);

  memristor_kernel<<<dim3(32, 4, 4), dim3(512), 0, stream>>>(
      x, w_pos, w_neg, b_pos, b_neg, n_param, wsf, y);
}